// Round 4
// baseline (201.699 us; speedup 1.0000x reference)
//
#include <hip/hip_runtime.h>
#include <hip/hip_bf16.h>

#define HIDDEN 4096
#define INTER 11008
#define MTOK 128  // 4*32 tokens

typedef float f32x4 __attribute__((ext_vector_type(4)));
typedef short s16x8 __attribute__((ext_vector_type(8)));
typedef __attribute__((address_space(3))) unsigned int as3_u32;
typedef __attribute__((address_space(1))) unsigned int as1_u32;

__device__ __forceinline__ unsigned short f2bf(float f) {
    unsigned int u = __float_as_uint(f);
    u += 0x7FFFu + ((u >> 16) & 1u);
    return (unsigned short)(u >> 16);
}

__device__ __forceinline__ s16x8 cvt8(f32x4 a, f32x4 b) {
    s16x8 r;
    r[0] = (short)f2bf(a[0]); r[1] = (short)f2bf(a[1]);
    r[2] = (short)f2bf(a[2]); r[3] = (short)f2bf(a[3]);
    r[4] = (short)f2bf(b[0]); r[5] = (short)f2bf(b[1]);
    r[6] = (short)f2bf(b[2]); r[7] = (short)f2bf(b[3]);
    return r;
}

// ---------------- kernel 1: x fp32 -> bf16 in MFMA FRAGMENT ORDER ----------------
// Group g = ((s*8 + mt)*2 + kk2)*64 + lane holds 8 bf16:
//   x[mt*16 + (lane&15)][s*64 + kk2*32 + (lane>>4)*8 + e], e=0..7
// so a wave's A-frag load for (s,mt,kk2) is ONE coalesced 1KB dwordx4 group.
__global__ __launch_bounds__(256) void k_convert_x2(const float* __restrict__ x,
                                                    s16x8* __restrict__ xf) {
    int t = blockIdx.x * 256 + threadIdx.x;  // [0, 65536)
    int lane = t & 63, kk2 = (t >> 6) & 1, mt = (t >> 7) & 7, s = t >> 10;
    int row = mt * 16 + (lane & 15);
    int k0 = s * 64 + kk2 * 32 + (lane >> 4) * 8;
    const float* p = x + (size_t)row * HIDDEN + k0;
    f32x4 a = *reinterpret_cast<const f32x4*>(p);
    f32x4 b = *reinterpret_cast<const f32x4*>(p + 4);
    xf[t] = cvt8(a, b);
}

// per-wave weight DMA: 16 rows x 64 f32 (4KB), 256B contiguous per row,
// XOR(row&7)<<4 swizzle on GLOBAL SOURCE (LDS dest linear). 4 instrs.
__device__ __forceinline__ void dma_w(const float* w, int n0, int wv, int lane,
                                      int s, float* dst) {
    const int r16 = lane & 15, g4 = lane >> 4;
#pragma unroll
    for (int j = 0; j < 4; ++j) {
        int row = wv * 16 + j * 4 + g4;
        const float* src = w + (size_t)(n0 + row) * HIDDEN + s * 64 + ((r16 ^ (row & 7)) << 2);
        __builtin_amdgcn_global_load_lds((as1_u32*)src,
                                         (as3_u32*)(dst + (wv * 16 + j * 4) * 64), 16, 0, 0);
    }
}

// ---------------- kernel 2: gate & up GEMM, barrier-free per-wave pipeline ----
// grid.x = 172 * 2 * Sg ; block = 256 (4 waves). Each wave owns 16 weight rows,
// double-buffers them in its private LDS region; A-frags read from frag-ordered
// xf (L2-resident). No __syncthreads in the kernel.
__global__ __launch_bounds__(256, 4) void k_gateup4(const s16x8* __restrict__ xf,
                                                    const float* __restrict__ wg,
                                                    const float* __restrict__ wu,
                                                    float* __restrict__ pg,
                                                    float* __restrict__ pu, int Sg) {
    __shared__ __align__(16) float wlds[2][64 * 64];  // 32 KB
    const int tid = threadIdx.x, wv = tid >> 6, lane = tid & 63;
    const int r16 = lane & 15, g4 = lane >> 4;
    const int gid = blockIdx.x;
    const int nt = gid % 172, rest = gid / 172;
    const int mat = rest & 1, kc = rest >> 1;
    const int n0 = nt * 64;
    const int nk = (HIDDEN / 64) / Sg;
    const int sbeg = kc * nk, send = (kc + 1) * nk;

    const float* w = mat ? wu : wg;

    f32x4 acc[8];
#pragma unroll
    for (int i = 0; i < 8; ++i) acc[i] = (f32x4)0.0f;

    dma_w(w, n0, wv, lane, sbeg, wlds[0]);

    for (int s = sbeg; s < send; ++s) {
        const int buf = (s - sbeg) & 1;
        if (s + 1 < send) {
            dma_w(w, n0, wv, lane, s + 1, wlds[buf ^ 1]);
            asm volatile("s_waitcnt vmcnt(4)" ::: "memory");  // cur landed; next in flight
        } else {
            asm volatile("s_waitcnt vmcnt(0)" ::: "memory");
        }
        const char* wrow = (const char*)&wlds[buf][(wv * 16 + r16) * 64];
        const unsigned swz = (unsigned)((r16 & 7) << 4);
        const s16x8* ab = xf + (size_t)s * 1024 + lane;
#pragma unroll
        for (int kk2 = 0; kk2 < 2; ++kk2) {
            f32x4 b0 = *reinterpret_cast<const f32x4*>(wrow + (((kk2 * 32 + g4 * 8) * 4) ^ swz));
            f32x4 b1 = *reinterpret_cast<const f32x4*>(wrow + (((kk2 * 32 + g4 * 8 + 4) * 4) ^ swz));
            s16x8 bf = cvt8(b0, b1);
#pragma unroll
            for (int mt = 0; mt < 8; ++mt) {
                s16x8 af = ab[(mt * 2 + kk2) * 64];
                acc[mt] = __builtin_amdgcn_mfma_f32_16x16x32_bf16(af, bf, acc[mt], 0, 0, 0);
            }
        }
    }

    float* p = (mat ? pu : pg) + (size_t)kc * (MTOK * INTER);
#pragma unroll
    for (int mt = 0; mt < 8; ++mt)
#pragma unroll
        for (int r = 0; r < 4; ++r) {
            int m = mt * 16 + g4 * 4 + r;
            p[(size_t)m * INTER + n0 + wv * 16 + r16] = acc[mt][r];
        }
}

// ---------------- down-path GEMM body (unchanged from round 3) ----------------
template <int LDK>
__device__ __forceinline__ void gemm_body(const unsigned short* __restrict__ ab,
                                          const float* __restrict__ w, int n0,
                                          int sbeg, int send, float acc_out[8][4],
                                          unsigned short* xs, float* wlds) {
    const int tid = threadIdx.x;
    const int wv = tid >> 6, lane = tid & 63;
    const int r16 = lane & 15, g4 = lane >> 4;

    f32x4 acc[8];
#pragma unroll
    for (int i = 0; i < 8; ++i) acc[i] = (f32x4)0.0f;

    const int wrow_b = wv * 16;

    for (int s = sbeg; s < send; ++s) {
        const int k0 = s * 64;
        __syncthreads();
#pragma unroll
        for (int j = 0; j < 4; ++j) {
            int row = wrow_b + j * 4 + g4;
            const float* src = w + (size_t)(n0 + row) * LDK + k0 + (((lane & 15) ^ (row & 7)) << 2);
            __builtin_amdgcn_global_load_lds((as1_u32*)src, (as3_u32*)&wlds[(wrow_b + j * 4) * 64],
                                             16, 0, 0);
        }
#pragma unroll
        for (int i = 0; i < 4; ++i) {
            int u = tid + i * 256, row = u >> 3, off = u & 7;
            *reinterpret_cast<uint4*>(&xs[row * 72 + off * 8]) =
                *reinterpret_cast<const uint4*>(ab + (size_t)row * LDK + k0 + off * 8);
        }
        __syncthreads();
        const char* wrow = (const char*)&wlds[(wv * 16 + r16) * 64];
        const unsigned swz = (unsigned)((r16 & 7) << 4);
#pragma unroll
        for (int kk = 0; kk < 64; kk += 32) {
            f32x4 b0 = *reinterpret_cast<const f32x4*>(wrow + ((unsigned)((kk + g4 * 8) * 4) ^ swz));
            f32x4 b1 = *reinterpret_cast<const f32x4*>(wrow + ((unsigned)((kk + g4 * 8 + 4) * 4) ^ swz));
            s16x8 bf = cvt8(b0, b1);
#pragma unroll
            for (int mt = 0; mt < 8; ++mt) {
                s16x8 af = *reinterpret_cast<const s16x8*>(&xs[(mt * 16 + r16) * 72 + kk + g4 * 8]);
                acc[mt] = __builtin_amdgcn_mfma_f32_16x16x32_bf16(af, bf, acc[mt], 0, 0, 0);
            }
        }
    }
#pragma unroll
    for (int mt = 0; mt < 8; ++mt)
#pragma unroll
        for (int r = 0; r < 4; ++r) acc_out[mt][r] = acc[mt][r];
}

// ---------------- kernel 3: combine partials + silu*up -> hb bf16 ----------------
__global__ __launch_bounds__(256) void k_combine(const float* __restrict__ pg,
                                                 const float* __restrict__ pu,
                                                 unsigned short* __restrict__ hb, int Sg) {
    size_t i = (size_t)(blockIdx.x * 256 + threadIdx.x) * 4;
    f32x4 g = (f32x4)0.0f, u = (f32x4)0.0f;
    for (int c = 0; c < Sg; ++c) {
        g += *reinterpret_cast<const f32x4*>(pg + (size_t)c * (MTOK * INTER) + i);
        u += *reinterpret_cast<const f32x4*>(pu + (size_t)c * (MTOK * INTER) + i);
    }
    ushort4 o;
    o.x = f2bf(g[0] / (1.0f + __expf(-g[0])) * u[0]);
    o.y = f2bf(g[1] / (1.0f + __expf(-g[1])) * u[1]);
    o.z = f2bf(g[2] / (1.0f + __expf(-g[2])) * u[2]);
    o.w = f2bf(g[3] / (1.0f + __expf(-g[3])) * u[3]);
    *reinterpret_cast<ushort4*>(hb + i) = o;
}

// ---------------- kernel 4: down GEMM (unchanged) ----------------
__global__ __launch_bounds__(256, 4) void k_down3(const unsigned short* __restrict__ hb,
                                                  const float* __restrict__ wd,
                                                  float* __restrict__ pd, int Sd) {
    __shared__ __align__(16) unsigned short xs[MTOK * 72];
    __shared__ __align__(16) float wlds[64 * 64];
    const int gid = blockIdx.x;
    const int nt = gid % 64, kc = gid / 64;
    const int n0 = nt * 64;
    const int sbeg = (172 * kc) / Sd, send = (172 * (kc + 1)) / Sd;

    float acc[8][4];
    gemm_body<INTER>(hb, wd, n0, sbeg, send, acc, xs, wlds);

    const int lane = threadIdx.x & 63, wv = threadIdx.x >> 6;
    const int r16 = lane & 15, g4 = lane >> 4;
    float* p = pd + (size_t)kc * (MTOK * HIDDEN);
#pragma unroll
    for (int mt = 0; mt < 8; ++mt)
#pragma unroll
        for (int r = 0; r < 4; ++r) {
            int m = mt * 16 + g4 * 4 + r;
            p[(size_t)m * HIDDEN + n0 + wv * 16 + r16] = acc[mt][r];
        }
}

// ---------------- kernel 5: reduce Sd partials -> out ----------------
__global__ __launch_bounds__(256) void k_reduce(const float* __restrict__ pd,
                                                float* __restrict__ out, int Sd) {
    int i = (blockIdx.x * 256 + threadIdx.x) * 4;
    const int NT = MTOK * HIDDEN;
    f32x4 s = (f32x4)0.0f;
    for (int c = 0; c < Sd; ++c)
        s += *reinterpret_cast<const f32x4*>(pd + (size_t)c * NT + i);
    *reinterpret_cast<f32x4*>(out + i) = s;
}

extern "C" void kernel_launch(void* const* d_in, const int* in_sizes, int n_in,
                              void* d_out, int out_size, void* d_ws, size_t ws_size,
                              hipStream_t stream) {
    const float* x  = (const float*)d_in[0];
    const float* wg = (const float*)d_in[1];
    const float* wu = (const float*)d_in[2];
    const float* wd = (const float*)d_in[3];
    float* out = (float*)d_out;

    const size_t XB = 1048576;
    const size_t HB = 2818048;
    const size_t PGU = (size_t)MTOK * INTER * 4;
    const size_t PD  = (size_t)MTOK * HIDDEN * 4;
    const int cfg[5][2] = {{4, 16}, {4, 8}, {2, 8}, {2, 4}, {1, 2}};
    int Sg = 1, Sd = 2;
    for (int c = 0; c < 5; ++c) {
        size_t need = XB + HB + 2 * (size_t)cfg[c][0] * PGU + (size_t)cfg[c][1] * PD;
        if (need <= ws_size) { Sg = cfg[c][0]; Sd = cfg[c][1]; break; }
    }

    char* ws = (char*)d_ws;
    s16x8* xf = (s16x8*)ws;                               // frag-ordered x, 1 MB
    unsigned short* hb = (unsigned short*)(ws + XB);
    float* pg = (float*)(ws + XB + HB);
    float* pu = pg + (size_t)Sg * (MTOK * INTER);
    float* pd = pu + (size_t)Sg * (MTOK * INTER);

    k_convert_x2<<<256, 256, 0, stream>>>(x, xf);
    k_gateup4<<<172 * 2 * Sg, 256, 0, stream>>>(xf, wg, wu, pg, pu, Sg);
    k_combine<<<1376, 256, 0, stream>>>(pg, pu, hb, Sg);
    k_down3<<<64 * Sd, 256, 0, stream>>>(hb, wd, pd, Sd);
    k_reduce<<<512, 256, 0, stream>>>(pd, out, Sd);
}